// Round 7
// baseline (156.422 us; speedup 1.0000x reference)
//
#include <hip/hip_runtime.h>
#include <hip/hip_bf16.h>
#include <math.h>

// Problem constants (from reference setup_inputs)
constexpr int B_  = 192;
constexpr int NY  = 48;
constexpr int NT  = 48;
constexpr int C_  = 6625;
constexpr int EPB = NT * NY;               // 2304 elements per (b, array)
constexpr unsigned long long MAGIC = 0x5AF00DD5C0FFEE11ULL;

// DPP move helper (compile-time ctrl). Invalid/masked lanes get `identity`.
template<int CTRL, int RM>
__device__ __forceinline__ float dpp_movf(float identity, float x) {
    int r = __builtin_amdgcn_update_dpp(__builtin_bit_cast(int, identity),
                                        __builtin_bit_cast(int, x),
                                        CTRL, RM, 0xf, false);
    return __builtin_bit_cast(float, r);
}
// ctrl: ROW_SHR|n = 0x110|n, WAVE_SHR1 = 0x138, ROW_BCAST15 = 0x142, ROW_BCAST31 = 0x143

// Single-node kernel. 4 blocks per b: quarters g=0..2 gather+publish; g=3
// gathers its quarter, then scans the whole b; the b==191 scanner reduces.
// Sync via per-block 64-bit MAGIC release-store flags (no RMW chains, no
// memset node: correctness holds for arbitrary initial ws content, since
// replay writes are bit-identical to any previously published values).
__global__ __launch_bounds__(256) void ep_onekernel(
    const float* __restrict__ pred,
    const float* __restrict__ R,
    const float* __restrict__ I,
    const int*   __restrict__ tgt,
    float* __restrict__ wsP,
    float* __restrict__ wsI,
    unsigned long long* __restrict__ qflag,   // [B_*4]
    float* __restrict__ logs,                 // [B_]
    unsigned long long* __restrict__ lflag,   // [B_]
    float* __restrict__ out)
{
    __shared__ float sP[NT][NY];
    __shared__ float sI[NT][NY];
    __shared__ int   sTT[NT];
    __shared__ float sRed[4];

    const int tid = threadIdx.x;
    const int bid = blockIdx.x;
    const int b   = bid >> 2;
    const int g   = bid & 3;

    // ---- Phase 1: gather this block's quarter (576 P + 576 I), write to ws ----
    const float* predB = pred + (size_t)b * NY * C_;
    const float* IB    = I    + (size_t)b * NY * C_;
    float* wP = wsP + (size_t)b * EPB;
    float* wI = wsI + (size_t)b * EPB;
    #pragma unroll
    for (int k = 0; k < 3; ++k) {
        int il = tid + k * 256;
        if (il < 576) {
            int i = g * 576 + il;            // i in [g*576, (g+1)*576)
            int t = i / NY;
            int j = i - t * NY;
            int c = tgt[b * NT + t];
            size_t off = (size_t)j * C_ + (size_t)c;
            wP[i] = fmaxf(__builtin_nontemporal_load(predB + off), 0.0f);
            wI[i] = fmaxf(__builtin_nontemporal_load(IB + off),    0.0f);
        }
    }
    __threadfence();        // each thread: drain + publish its own stores
    __syncthreads();        // now ALL of this block's stores are agent-visible

    if (g != 3) {
        // Pure writer: publish quarter-done flag (plain release store, no RMW).
        if (tid == 0)
            __hip_atomic_store(&qflag[b * 4 + g], MAGIC,
                               __ATOMIC_RELEASE, __HIP_MEMORY_SCOPE_AGENT);
        return;
    }

    // ---- Scanner block (g==3) ----
    // Overlap: R / tgt loads issued while waiting for partners.
    float R0 = 0.0f, R1v = 0.0f, R2v = 0.0f;
    if (tid < NY) {
        const float* Rb = R + ((size_t)b * NY + tid) * 3;
        R0  = Rb[0];
        R1v = Rb[1];
        R2v = Rb[2];
    }
    if (tid < NT) sTT[tid] = tgt[b * NT + tid];
    if (tid < 3) {
        while (__hip_atomic_load(&qflag[b * 4 + tid], __ATOMIC_ACQUIRE,
                                 __HIP_MEMORY_SCOPE_AGENT) != MAGIC) { }
    }
    __syncthreads();

    // Stage the full b tile from ws (L2-hot) into LDS, float4-coalesced.
    const float4* p4 = (const float4*)wP;
    const float4* i4 = (const float4*)wI;
    float4* sp4 = (float4*)&sP[0][0];
    float4* si4 = (float4*)&sI[0][0];
    #pragma unroll
    for (int k = 0; k < 3; ++k) {
        int idx = tid + k * 256;
        if (idx < EPB / 4) {             // 576 float4 per array
            sp4[idx] = p4[idx];
            si4[idx] = i4[idx];
        }
    }
    __syncthreads();

    // ---- Phase 2: DPP affine-scan recurrence (wave 0, lanes 0..47) ----
    if (tid < NY) {
        const int j = tid;
        float Imult  = (j == NY - 1) ? 1.0f : R1v;
        float R2prev = dpp_movf<0x138, 0xf>(0.0f, R2v);   // R2[j-1]

        // row0: multiplicative scan of d0 = (tgt[0]==1) ? 1 : R2
        float d0 = (sTT[0] == 1) ? 1.0f : R2v;
        float v  = (j == 0) ? 1.0f : d0;
        v *= dpp_movf<0x111, 0xf>(1.0f, v);
        v *= dpp_movf<0x112, 0xf>(1.0f, v);
        v *= dpp_movf<0x114, 0xf>(1.0f, v);
        v *= dpp_movf<0x118, 0xf>(1.0f, v);
        v *= dpp_movf<0x142, 0xa>(1.0f, v);
        v *= dpp_movf<0x143, 0xc>(1.0f, v);
        float row = v;

        float pg = sP[0][j];
        float ig = sI[0][j];
        for (int t = 0; t < NT - 1; ++t) {
            float pgn = sP[t + 1][j];     // prefetch next iteration
            float ign = sI[t + 1][j];

            // a[j] = row[j]*pI[j] + row[j-1]*pC[j-1]
            float u  = row * (R0 * pg);
            float up = dpp_movf<0x138, 0xf>(0.0f, u);
            float c  = fmaf(row, Imult * ig, up);
            float m  = (j == 0) ? 0.0f : ((sTT[t + 1] == 1) ? 1.0f : R2prev);

            // inclusive affine-map scan (validated DPP pattern)
            { float mp = dpp_movf<0x111, 0xf>(1.0f, m), cp = dpp_movf<0x111, 0xf>(0.0f, c); c = fmaf(m, cp, c); m *= mp; }
            { float mp = dpp_movf<0x112, 0xf>(1.0f, m), cp = dpp_movf<0x112, 0xf>(0.0f, c); c = fmaf(m, cp, c); m *= mp; }
            { float mp = dpp_movf<0x114, 0xf>(1.0f, m), cp = dpp_movf<0x114, 0xf>(0.0f, c); c = fmaf(m, cp, c); m *= mp; }
            { float mp = dpp_movf<0x118, 0xf>(1.0f, m), cp = dpp_movf<0x118, 0xf>(0.0f, c); c = fmaf(m, cp, c); m *= mp; }
            { float mp = dpp_movf<0x142, 0xa>(1.0f, m), cp = dpp_movf<0x142, 0xa>(0.0f, c); c = fmaf(m, cp, c); m *= mp; }
            { float mp = dpp_movf<0x143, 0xc>(1.0f, m), cp = dpp_movf<0x143, 0xc>(0.0f, c); c = fmaf(m, cp, c); m *= mp; }
            row = c;

            pg = pgn; ig = ign;
        }

        if (j == NY - 1) {
            logs[b] = logf(row);
            __hip_atomic_store(&lflag[b], MAGIC,
                               __ATOMIC_RELEASE, __HIP_MEMORY_SCOPE_AGENT);
        }
    }

    // ---- b==191 scanner: deterministic fixed-order mean of 192 logs ----
    if (b == B_ - 1) {
        __syncthreads();                 // all 256 threads of this block
        float x = 0.0f;
        if (tid < B_) {
            while (__hip_atomic_load(&lflag[tid], __ATOMIC_ACQUIRE,
                                     __HIP_MEMORY_SCOPE_AGENT) != MAGIC) { }
            x = logs[tid];
        }
        #pragma unroll
        for (int s = 1; s < 64; s <<= 1) x += __shfl_xor(x, s);
        if ((tid & 63) == 0) sRed[tid >> 6] = (tid < B_) ? x : 0.0f;
        __syncthreads();
        if (tid == 0) out[0] = (sRed[0] + sRed[1] + sRed[2]) * (1.0f / (float)B_);
    }
}

extern "C" void kernel_launch(void* const* d_in, const int* in_sizes, int n_in,
                              void* d_out, int out_size, void* d_ws, size_t ws_size,
                              hipStream_t stream) {
    const float* pred = (const float*)d_in[0];
    const float* R    = (const float*)d_in[1];
    const float* I    = (const float*)d_in[2];
    const int*   tgt  = (const int*)d_in[3];
    float* out = (float*)d_out;

    char* ws = (char*)d_ws;
    float* wsP                 = (float*)(ws);                      // 192*2304 f
    float* wsI                 = (float*)(ws + 1769472);            // 192*2304 f
    unsigned long long* qflag  = (unsigned long long*)(ws + 3538944);  // 768 u64
    float* logs                = (float*)(ws + 3545088);            // 192 f
    unsigned long long* lflag  = (unsigned long long*)(ws + 3545856);  // 192 u64
    // end: 3547392 bytes

    ep_onekernel<<<B_ * 4, 256, 0, stream>>>(pred, R, I, tgt,
                                             wsP, wsI, qflag, logs, lflag, out);
}

// Round 8
// 30.858 us; speedup vs baseline: 5.0691x; 5.0691x over previous
//
#include <hip/hip_runtime.h>
#include <hip/hip_bf16.h>
#include <math.h>

// Problem constants (from reference setup_inputs)
constexpr int B_  = 192;
constexpr int NY  = 48;
constexpr int NT  = 48;
constexpr int C_  = 6625;

// DPP move helper (compile-time ctrl). Invalid/masked lanes get `identity`.
template<int CTRL, int RM>
__device__ __forceinline__ float dpp_movf(float identity, float x) {
    int r = __builtin_amdgcn_update_dpp(__builtin_bit_cast(int, identity),
                                        __builtin_bit_cast(int, x),
                                        CTRL, RM, 0xf, false);
    return __builtin_bit_cast(float, r);
}
// ctrl: ROW_SHR|n = 0x110|n, WAVE_SHR1 = 0x138, ROW_BCAST15 = 0x142, ROW_BCAST31 = 0x143

// One block per b. All 18 scattered loads issued up front (MSHR-filling);
// LDS commit in 9 chunks; wave 0 interleaves the DPP affine scan over rows
// that are complete after each chunk barrier -> scan hides under gather.
// Row-race-free: after barrier k, scan reads rows < floor((k+1)*16/3); chunk
// k+1 writes only rows >= floor((k+1)*16/3).
__global__ __launch_bounds__(256) void ep_fwd_kernel(
    const float* __restrict__ pred,
    const float* __restrict__ R,
    const float* __restrict__ I,
    const int*   __restrict__ tgt,
    float* __restrict__ out)
{
    __shared__ float sP[NT][NY];
    __shared__ float sI[NT][NY];
    __shared__ int   sT[NT];

    const int b   = blockIdx.x;
    const int tid = threadIdx.x;

    if (tid < NT) sT[tid] = tgt[b * NT + tid];
    float R0 = 0.0f, R1v = 0.0f, R2v = 0.0f;
    if (tid < NY) {
        const float* Rb = R + ((size_t)b * NY + tid) * 3;
        R0  = Rb[0];
        R1v = Rb[1];
        R2v = Rb[2];
    }
    __syncthreads();

    // ---- Issue all 18 scattered loads (R1's measured-best pattern) ----
    const float* predB = pred + (size_t)b * NY * C_;
    const float* IB    = I    + (size_t)b * NY * C_;
    float vP[9], vI[9];
    int   tt[9], jj[9];
    #pragma unroll
    for (int k = 0; k < 9; ++k) {
        int e = tid + k * 256;           // e in [0, 2304)
        int t = e / NY;
        int j = e - t * NY;
        tt[k] = t; jj[k] = j;
        size_t off = (size_t)j * C_ + (size_t)sT[t];
        vP[k] = predB[off];
        vI[k] = IB[off];
    }

    // ---- Scan init (wave 0; exec-masked exactly as validated in R2/R3) ----
    float Imult = 1.0f, R2prev = 0.0f, row = 0.0f;
    if (tid < NY) {
        Imult  = (tid == NY - 1) ? 1.0f : R1v;
        R2prev = dpp_movf<0x138, 0xf>(0.0f, R2v);        // R2[j-1]
        float d0 = (sT[0] == 1) ? 1.0f : R2v;
        float v  = (tid == 0) ? 1.0f : d0;
        v *= dpp_movf<0x111, 0xf>(1.0f, v);
        v *= dpp_movf<0x112, 0xf>(1.0f, v);
        v *= dpp_movf<0x114, 0xf>(1.0f, v);
        v *= dpp_movf<0x118, 0xf>(1.0f, v);
        v *= dpp_movf<0x142, 0xa>(1.0f, v);
        v *= dpp_movf<0x143, 0xc>(1.0f, v);
        row = v;
    }

    // rows complete after chunk k: t < upto[k] = floor((k+1)*16/3), cap 47 steps
    constexpr int upto[9] = {5, 10, 16, 21, 26, 32, 37, 42, 47};

    int tcur = 0;
    #pragma unroll
    for (int k = 0; k < 9; ++k) {
        // commit chunk k to LDS (waits only on these 2 loads)
        sP[tt[k]][jj[k]] = fmaxf(vP[k], 0.0f);
        sI[tt[k]][jj[k]] = fmaxf(vI[k], 0.0f);
        __syncthreads();

        // wave 0: advance scan over newly-complete rows (hidden under gather)
        if (tid < NY) {
            const int j = tid;
            while (tcur < upto[k]) {
                const int t = tcur;
                float pg = sP[t][j];
                float ig = sI[t][j];

                // a[j] = row[j]*pI[j] + row[j-1]*pC[j-1]
                float u  = row * (R0 * pg);
                float up = dpp_movf<0x138, 0xf>(0.0f, u);
                float c  = fmaf(row, Imult * ig, up);
                float m  = (j == 0) ? 0.0f : ((sT[t + 1] == 1) ? 1.0f : R2prev);

                // inclusive affine-map scan (validated DPP pattern)
                { float mp = dpp_movf<0x111, 0xf>(1.0f, m), cp = dpp_movf<0x111, 0xf>(0.0f, c); c = fmaf(m, cp, c); m *= mp; }
                { float mp = dpp_movf<0x112, 0xf>(1.0f, m), cp = dpp_movf<0x112, 0xf>(0.0f, c); c = fmaf(m, cp, c); m *= mp; }
                { float mp = dpp_movf<0x114, 0xf>(1.0f, m), cp = dpp_movf<0x114, 0xf>(0.0f, c); c = fmaf(m, cp, c); m *= mp; }
                { float mp = dpp_movf<0x118, 0xf>(1.0f, m), cp = dpp_movf<0x118, 0xf>(0.0f, c); c = fmaf(m, cp, c); m *= mp; }
                { float mp = dpp_movf<0x142, 0xa>(1.0f, m), cp = dpp_movf<0x142, 0xa>(0.0f, c); c = fmaf(m, cp, c); m *= mp; }
                { float mp = dpp_movf<0x143, 0xc>(1.0f, m), cp = dpp_movf<0x143, 0xc>(0.0f, c); c = fmaf(m, cp, c); m *= mp; }
                row = c;
                ++tcur;
            }
        }
    }

    // ---- Tail: one scattered-in-time atomic per block; no chain, no spin ----
    if (tid == NY - 1) {
        atomicAdd(out, logf(row) * (1.0f / (float)B_));
    }
}

extern "C" void kernel_launch(void* const* d_in, const int* in_sizes, int n_in,
                              void* d_out, int out_size, void* d_ws, size_t ws_size,
                              hipStream_t stream) {
    const float* pred = (const float*)d_in[0];
    const float* R    = (const float*)d_in[1];
    const float* I    = (const float*)d_in[2];
    const int*   tgt  = (const int*)d_in[3];
    float* out = (float*)d_out;

    hipMemsetAsync(out, 0, sizeof(float), stream);   // graph-ordered before kernel
    ep_fwd_kernel<<<B_, 256, 0, stream>>>(pred, R, I, tgt, out);
}